// Round 1
// baseline (284.778 us; speedup 1.0000x reference)
//
#include <hip/hip_runtime.h>

// DynamicUpsamplingFilter: out[b,c,h,w] = sum_{dy,dx} f[b,3*dy+dx,h,w] * x[b,c,h+dy-1,w+dx-1]
// x: [B,128,180,320] f32, filters: [B,9,180,320] f32, out: [B,128,180,320] f32.
// Memory-bound (ideal ~245 MB HBM @ B=4 -> ~39 us). One thread = one float4 of
// outputs along W. Linear order (b, h, c, w4): consecutive blocks share filter
// rows (128-channel reuse -> L1/L2 hits) and x rows (h+-1 reuse -> L2 hits).

#define CC 128
#define HH 180
#define WW 320
#define W4 80
#define NF 9

__global__ __launch_bounds__(256) void duf_kernel(
    const float* __restrict__ x,
    const float* __restrict__ f,
    float* __restrict__ out,
    int total)
{
    int n = blockIdx.x * 256 + threadIdx.x;
    if (n >= total) return;

    int w4 = n % W4;
    int t  = n / W4;
    int c  = t % CC;
    t /= CC;
    int h  = t % HH;
    int b  = t / HH;

    const float4* x4 = (const float4*)x;
    const float4* f4 = (const float4*)f;

    // 9 per-pixel filter taps, vectorized over 4 output columns.
    float4 fr[NF];
    int fbase = (b * NF * HH + h) * W4 + w4;
#pragma unroll
    for (int i = 0; i < NF; ++i)
        fr[i] = f4[fbase + i * (HH * W4)];

    float4 acc = make_float4(0.f, 0.f, 0.f, 0.f);
    int xchan4 = (b * CC + c) * HH * W4;  // channel base, float4 units

#pragma unroll
    for (int dy = 0; dy < 3; ++dy) {
        int hh = h + dy - 1;
        float4 xc = make_float4(0.f, 0.f, 0.f, 0.f);
        float xl = 0.f, xr = 0.f;
        if (hh >= 0 && hh < HH) {
            int rb4 = xchan4 + hh * W4;
            xc = x4[rb4 + w4];
            const float* rowf = x + (size_t)rb4 * 4;
            if (w4 > 0)      xl = rowf[w4 * 4 - 1];
            if (w4 < W4 - 1) xr = rowf[w4 * 4 + 4];
        }
        float4 f0 = fr[3 * dy + 0];
        float4 f1 = fr[3 * dy + 1];
        float4 f2 = fr[3 * dy + 2];
        // output column j uses x[w+j-1], x[w+j], x[w+j+1]
        acc.x = fmaf(f0.x, xl,   fmaf(f1.x, xc.x, fmaf(f2.x, xc.y, acc.x)));
        acc.y = fmaf(f0.y, xc.x, fmaf(f1.y, xc.y, fmaf(f2.y, xc.z, acc.y)));
        acc.z = fmaf(f0.z, xc.y, fmaf(f1.z, xc.z, fmaf(f2.z, xc.w, acc.z)));
        acc.w = fmaf(f0.w, xc.z, fmaf(f1.w, xc.w, fmaf(f2.w, xr,   acc.w)));
    }

    ((float4*)out)[(size_t)((b * CC + c) * HH + h) * W4 + w4] = acc;
}

extern "C" void kernel_launch(void* const* d_in, const int* in_sizes, int n_in,
                              void* d_out, int out_size, void* d_ws, size_t ws_size,
                              hipStream_t stream) {
    const float* x = (const float*)d_in[0];
    const float* f = (const float*)d_in[1];
    float* out = (float*)d_out;

    int B = in_sizes[0] / (CC * HH * WW);  // 4
    int total = B * CC * HH * W4;          // float4 outputs
    int blocks = (total + 255) / 256;

    duf_kernel<<<blocks, 256, 0, stream>>>(x, f, out, total);
}